// Round 12
// baseline (7608.359 us; speedup 1.0000x reference)
//
#include <hip/hip_runtime.h>
#include <cstdint>
#include <cstddef>

#define SEQ     100
#define BATCH   2048
#define IN_DIM  64
#define MID_I   60
#define LATENT  20
#define V_MID   800
#define V_LAT   50
#define MID_O   800
#define OUT_DIM 512

#define KP4  896    // [h_t pad 64 | h2 800 | pad to 896]
#define KP5  1344   // [h2 800 pad 832 | h3 512]
#define KPL1 2048   // latent*seq 2000 padded

using f32x4  = __attribute__((ext_vector_type(4))) float;
using f32x16 = __attribute__((ext_vector_type(16))) float;
using u16x8  = __attribute__((ext_vector_type(8))) unsigned short;
using bf16x8 = __attribute__((ext_vector_type(8))) __bf16;
typedef _Float16 f16;
typedef _Float16 f16x8 __attribute__((ext_vector_type(8)));

__device__ __forceinline__ unsigned short f2bf(float x){
    unsigned u = __builtin_bit_cast(unsigned, x);
    u += 0x7FFFu + ((u >> 16) & 1u);
    return (unsigned short)(u >> 16);
}
__device__ __forceinline__ float bf2f(unsigned short b){
    unsigned u = ((unsigned)b) << 16; return __builtin_bit_cast(float, u);
}
__device__ __forceinline__ float sigm(float x){ return 1.f/(1.f+__expf(-x)); }
__device__ __forceinline__ float tanh_f(float x){ return 1.f - 2.f/(__expf(2.f*x)+1.f); }

typedef const __attribute__((address_space(1))) unsigned int* gas_ptr;
typedef __attribute__((address_space(3))) unsigned int* las_ptr;
__device__ __forceinline__ void gld16(const void* g, char* l) {
    __builtin_amdgcn_global_load_lds((gas_ptr)g, (las_ptr)l, 16, 0, 0);
}

// ---------------------------------------------------------------------------
// fp32 tiled GEMM (lin2, decoder init only)
// ---------------------------------------------------------------------------
constexpr int BM = 64, BN = 64, BK = 16;
template<bool RELU_A1, bool RELU_OUT>
__global__ __launch_bounds__(256)
void gemm2k(const float* __restrict__ A1, int K1,
            const float* __restrict__ A2, int K2,
            const float* __restrict__ W1, const float* __restrict__ W2,
            const float* __restrict__ b1, const float* __restrict__ b2,
            float* __restrict__ C, int M, int N)
{
    __shared__ float As[BK][BM + 1];
    __shared__ float Bs[BK][BN + 1];
    const int tx = threadIdx.x & 15;
    const int ty = threadIdx.x >> 4;
    const int n0 = blockIdx.x * BN;
    const int m0 = blockIdx.y * BM;

    float acc[4][4] = {};

    for (int src = 0; src < 2; ++src) {
        const float* A = src ? A2 : A1;
        const float* W = src ? W2 : W1;
        const int    K = src ? K2 : K1;
        if (A == nullptr || K == 0) continue;
        for (int k0 = 0; k0 < K; k0 += BK) {
            #pragma unroll
            for (int i = 0; i < 4; ++i) {
                int idx = threadIdx.x + i * 256;
                int k = idx & 15, m = idx >> 4;
                int gm = m0 + m, gk = k0 + k;
                float v = 0.f;
                if (gm < M && gk < K) v = A[(size_t)gm * K + gk];
                if (RELU_A1 && src == 0) v = fmaxf(v, 0.f);
                As[k][m] = v;
            }
            #pragma unroll
            for (int i = 0; i < 4; ++i) {
                int idx = threadIdx.x + i * 256;
                int k = idx & 15, n = idx >> 4;
                int gn = n0 + n, gk = k0 + k;
                float v = 0.f;
                if (gn < N && gk < K) v = W[(size_t)gn * K + gk];
                Bs[k][n] = v;
            }
            __syncthreads();
            #pragma unroll
            for (int kk = 0; kk < BK; ++kk) {
                float a[4], b[4];
                #pragma unroll
                for (int i = 0; i < 4; ++i) a[i] = As[kk][ty + i * 16];
                #pragma unroll
                for (int j = 0; j < 4; ++j) b[j] = Bs[kk][tx + j * 16];
                #pragma unroll
                for (int i = 0; i < 4; ++i)
                    #pragma unroll
                    for (int j = 0; j < 4; ++j)
                        acc[i][j] += a[i] * b[j];
            }
            __syncthreads();
        }
    }

    #pragma unroll
    for (int i = 0; i < 4; ++i) {
        int gm = m0 + ty + i * 16;
        if (gm >= M) continue;
        #pragma unroll
        for (int j = 0; j < 4; ++j) {
            int gn = n0 + tx + j * 16;
            if (gn >= N) continue;
            float v = acc[i][j];
            if (b1) v += b1[gn];
            if (b2) v += b2[gn];
            if (RELU_OUT) v = fmaxf(v, 0.f);
            C[(size_t)gm * N + gn] = v;
        }
    }
}

// ---------------------------------------------------------------------------
// split-bf16 3-term MFMA GEMM, 128x128 tile, plain fp32 store (+opt relu).
// Used for lin1 and the encoder projections.
// ---------------------------------------------------------------------------
template<bool RELU>
__global__ __launch_bounds__(256, 2)
void gemm_mfma0(const unsigned short* __restrict__ Ah, const unsigned short* __restrict__ Al,
                const unsigned short* __restrict__ Bh, const unsigned short* __restrict__ Bl,
                int Kp, int Nstore, const float* __restrict__ bi, float* __restrict__ Cout)
{
    __shared__ __align__(16) char smem[32768];
    const int tid  = threadIdx.x;
    const int lane = tid & 63;
    const int wid  = tid >> 6;
    const int m0   = blockIdx.y * 128;
    const int n0   = blockIdx.x * 128;
    const int wr   = (wid >> 1) << 6;
    const int wc   = (wid & 1) << 6;
    const int fr   = lane & 15;
    const int fg   = lane >> 4;
    const int slotR = ((fg ^ (fr & 3)) << 4);

    const int r0 = 32 * wid + (lane >> 2);
    const int sl = (((lane & 3) ^ ((lane >> 2) & 3)) << 3);
    const unsigned short* gA0h = Ah + (size_t)(m0 + r0)      * Kp + sl;
    const unsigned short* gA1h = Ah + (size_t)(m0 + r0 + 16) * Kp + sl;
    const unsigned short* gA0l = Al + (size_t)(m0 + r0)      * Kp + sl;
    const unsigned short* gA1l = Al + (size_t)(m0 + r0 + 16) * Kp + sl;
    const unsigned short* gB0h = Bh + (size_t)(n0 + r0)      * Kp + sl;
    const unsigned short* gB1h = Bh + (size_t)(n0 + r0 + 16) * Kp + sl;
    const unsigned short* gB0l = Bl + (size_t)(n0 + r0)      * Kp + sl;
    const unsigned short* gB1l = Bl + (size_t)(n0 + r0 + 16) * Kp + sl;
    char* lA0h = smem +     0 + (2 * wid    ) * 1024;
    char* lA1h = smem +     0 + (2 * wid + 1) * 1024;
    char* lA0l = smem +  8192 + (2 * wid    ) * 1024;
    char* lA1l = smem +  8192 + (2 * wid + 1) * 1024;
    char* lB0h = smem + 16384 + (2 * wid    ) * 1024;
    char* lB1h = smem + 16384 + (2 * wid + 1) * 1024;
    char* lB0l = smem + 24576 + (2 * wid    ) * 1024;
    char* lB1l = smem + 24576 + (2 * wid + 1) * 1024;

    f32x4 acc[4][4];
    #pragma unroll
    for (int i = 0; i < 4; ++i)
        #pragma unroll
        for (int j = 0; j < 4; ++j) acc[i][j] = (f32x4){0.f, 0.f, 0.f, 0.f};

    for (int k0 = 0; k0 < Kp; k0 += 32) {
        __syncthreads();
        gld16(gA0h + k0, lA0h); gld16(gA1h + k0, lA1h);
        gld16(gA0l + k0, lA0l); gld16(gA1l + k0, lA1l);
        gld16(gB0h + k0, lB0h); gld16(gB1h + k0, lB1h);
        gld16(gB0l + k0, lB0l); gld16(gB1l + k0, lB1l);
        __syncthreads();

        bf16x8 ah[4], al[4];
        #pragma unroll
        for (int i = 0; i < 4; ++i) {
            int ro = (wr + i * 16 + fr) * 64 + slotR;
            ah[i] = *(const bf16x8*)(smem +        ro);
            al[i] = *(const bf16x8*)(smem + 8192 + ro);
        }
        #pragma unroll
        for (int j = 0; j < 4; ++j) {
            int ro = (wc + j * 16 + fr) * 64 + slotR;
            bf16x8 fbh = *(const bf16x8*)(smem + 16384 + ro);
            bf16x8 fbl = *(const bf16x8*)(smem + 24576 + ro);
            #pragma unroll
            for (int i = 0; i < 4; ++i) {
                acc[i][j] = __builtin_amdgcn_mfma_f32_16x16x32_bf16(ah[i], fbh, acc[i][j], 0, 0, 0);
                acc[i][j] = __builtin_amdgcn_mfma_f32_16x16x32_bf16(ah[i], fbl, acc[i][j], 0, 0, 0);
                acc[i][j] = __builtin_amdgcn_mfma_f32_16x16x32_bf16(al[i], fbh, acc[i][j], 0, 0, 0);
            }
        }
    }

    #pragma unroll
    for (int j = 0; j < 4; ++j) {
        int gc = n0 + wc + j * 16 + fr;
        if (gc >= Nstore) continue;
        float badd = bi[gc];
        #pragma unroll
        for (int i = 0; i < 4; ++i)
            #pragma unroll
            for (int r = 0; r < 4; ++r) {
                int gr = m0 + wr + i * 16 + fg * 4 + r;
                float v = acc[i][j][r] + badd;
                if (RELU) v = fmaxf(v, 0.f);
                Cout[(size_t)gr * Nstore + gc] = v;
            }
    }
}

// ---------------------------------------------------------------------------
// decoder GEMM: fp16 MFMA 32x32x16, 128x128 tile, 4 waves, 3-buffer
// counted-vmcnt pipeline, LDS-transposed coalesced LSTM epilogue.
// LDS swizzle: slot = g ^ ((row>>1)&3)  (2-way max per 16-lane phase).
// XCD chunking over ROWS. Grid = NBX*NBYX*8 blocks. MODE 1 = l4, MODE 2 = l5.
// ---------------------------------------------------------------------------
template<int MODE>
__global__ __launch_bounds__(256, 3)
void gemm_dec(const f16* __restrict__ A, const f16* __restrict__ W,
              int Kp, int NK, int H, int NBYX,
              const float* __restrict__ bp,     // permuted combined bias [H*4]
              float* __restrict__ cstate,
              f16* __restrict__ wr1, int st1, int off1,
              f16* __restrict__ wr2, int st2, int off2,
              float* __restrict__ out_t)
{
    __shared__ __align__(16) char smem[49152];   // 3 buffers x (A 8K + W 8K)
    const int xcd = blockIdx.x & 7;
    const int ii  = blockIdx.x >> 3;
    const int by  = xcd * NBYX + (ii % NBYX);    // row-tile: L2-resident per XCD
    const int bx  = ii / NBYX;                   // col-tile: streamed
    const int m0 = by * 128;
    const int n0 = bx * 128;

    const int tid  = threadIdx.x;
    const int lane = tid & 63;
    const int wid  = tid >> 6;         // 0..3
    const int wm   = wid >> 1;         // 0..1
    const int wn   = wid & 1;          // 0..1
    const int l31  = lane & 31;
    const int l5   = lane >> 5;        // 0..1
    const int rsw  = (l31 >> 1) & 3;   // read-side row swizzle

    // staging: linear LDS dest; global source chunk = (lane&3) ^ ((lane>>3)&3)
    const int rbase = 32 * wid;
    const int lrow  = lane >> 2;
    const int chnk  = (lane & 3) ^ ((lane >> 3) & 3);
    const f16* sA0 = A + (size_t)(m0 + rbase + lrow)      * Kp + chnk * 8;
    const f16* sA1 = A + (size_t)(m0 + rbase + 16 + lrow) * Kp + chnk * 8;
    const f16* sW0 = W + (size_t)(n0 + rbase + lrow)      * Kp + chnk * 8;
    const f16* sW1 = W + (size_t)(n0 + rbase + 16 + lrow) * Kp + chnk * 8;

    f32x16 acc[2][2];
    #pragma unroll
    for (int i = 0; i < 2; ++i)
        #pragma unroll
        for (int j = 0; j < 2; ++j)
            #pragma unroll
            for (int q = 0; q < 16; ++q) acc[i][j][q] = 0.f;

    auto stage = [&](int t, int buf) {
        const int kb = t * 32;
        char* bb = smem + buf * 16384;
        gld16(sA0 + kb, bb + rbase * 64);
        gld16(sA1 + kb, bb + (rbase + 16) * 64);
        gld16(sW0 + kb, bb + 8192 + rbase * 64);
        gld16(sW1 + kb, bb + 8192 + (rbase + 16) * 64);
    };

    stage(0, 0);
    stage(1, 1);

    int buf = 0;
    for (int t = 0; t < NK; ++t) {
        if (t + 1 < NK) asm volatile("s_waitcnt vmcnt(4)" ::: "memory");
        else            asm volatile("s_waitcnt vmcnt(0)" ::: "memory");
        __builtin_amdgcn_s_barrier();
        if (t + 2 < NK) stage(t + 2, (buf + 2) % 3);
        const char* bb = smem + buf * 16384;
        // A frags: row = 64*wm + 32*i + l31; k-chunk g = 2s + l5, slot = g ^ rsw
        f16x8 a[2][2], b[2][2];
        #pragma unroll
        for (int i = 0; i < 2; ++i) {
            int base = (64 * wm + 32 * i + l31) * 64;
            a[i][0] = *(const f16x8*)(bb + base + ((l5     ^ rsw) << 4));
            a[i][1] = *(const f16x8*)(bb + base + (((2+l5) ^ rsw) << 4));
        }
        #pragma unroll
        for (int j = 0; j < 2; ++j) {
            int base = 8192 + (64 * wn + 32 * j + l31) * 64;
            b[j][0] = *(const f16x8*)(bb + base + ((l5     ^ rsw) << 4));
            b[j][1] = *(const f16x8*)(bb + base + (((2+l5) ^ rsw) << 4));
        }
        #pragma unroll
        for (int j = 0; j < 2; ++j)
            #pragma unroll
            for (int i = 0; i < 2; ++i) {
                acc[i][j] = __builtin_amdgcn_mfma_f32_32x32x16_f16(a[i][0], b[j][0], acc[i][j], 0, 0, 0);
                acc[i][j] = __builtin_amdgcn_mfma_f32_32x32x16_f16(a[i][1], b[j][1], acc[i][j], 0, 0, 0);
            }
        buf = (buf + 1) % 3;
    }

    // -------- epilogue: LDS gate transpose -> coalesced LSTM pointwise ----
    float* gt = (float*)smem;              // [64][132]
    const int u32 = tid & 31;              // unit within tile
    const int r8  = tid >> 5;              // 0..7
    const int unit = (n0 >> 2) + u32;
    const f32x4 bv = ((const f32x4*)bp)[unit];

    #pragma unroll
    for (int half = 0; half < 2; ++half) {
        __syncthreads();
        if (wm == half) {
            // C layout (32x32): col = l31, row = (q&3) + 8*(q>>2) + 4*l5
            #pragma unroll
            for (int i = 0; i < 2; ++i)
                #pragma unroll
                for (int j = 0; j < 2; ++j)
                    #pragma unroll
                    for (int q = 0; q < 16; ++q) {
                        int r = 32 * i + (q & 3) + 8 * (q >> 2) + 4 * l5;
                        gt[r * 132 + 64 * wn + 32 * j + l31] = acc[i][j][q];
                    }
        }
        __syncthreads();
        #pragma unroll
        for (int kk = 0; kk < 8; ++kk) {
            const int lr  = 8 * kk + r8;
            const int row = m0 + 64 * half + lr;
            f32x4 g = *(const f32x4*)(gt + lr * 132 + u32 * 4);
            float gi = g[0] + bv[0], gf = g[1] + bv[1];
            float gg = g[2] + bv[2], go = g[3] + bv[3];
            size_t ci = (size_t)row * H + unit;
            float cn = sigm(gf) * cstate[ci] + sigm(gi) * tanh_f(gg);
            float hn = sigm(go) * tanh_f(cn);
            cstate[ci] = cn;
            f16 hh = (f16)hn;
            wr1[(size_t)row * st1 + off1 + unit] = hh;
            if (MODE == 1) wr2[(size_t)row * st2 + off2 + unit] = hh;
            if (MODE == 2) out_t[(size_t)row * H + unit] = hn;
        }
    }
}

// ---------------------------------------------------------------------------
// packing kernels
// ---------------------------------------------------------------------------
__global__ void split_pack_lin1(const float* __restrict__ src,
                                unsigned short* __restrict__ dh, unsigned short* __restrict__ dl)
{
    int idx = blockIdx.x * blockDim.x + threadIdx.x;
    if (idx >= V_MID * LATENT * SEQ) return;
    int n = idx / (LATENT * SEQ), c = idx - n * (LATENT * SEQ);
    int l = c / SEQ, s = c - l * SEQ;
    float x = src[idx];
    unsigned short h = f2bf(x);
    size_t d = (size_t)n * KPL1 + s * LATENT + l;
    dh[d] = h;
    dl[d] = f2bf(x - bf2f(h));
}

// generic fp32 -> bf16 hi/lo, row-major [N][K] -> [N][Kp]
__global__ void split_pack_rows(const float* __restrict__ src, int total, int K, int Kp,
                                unsigned short* __restrict__ dh, unsigned short* __restrict__ dl)
{
    int idx = blockIdx.x * blockDim.x + threadIdx.x;
    if (idx >= total) return;
    int n = idx / K, k = idx - n * K;
    float x = src[idx];
    unsigned short h = f2bf(x);
    size_t d = (size_t)n * Kp + k;
    dh[d] = h;
    dl[d] = f2bf(x - bf2f(h));
}

// fp16 weight pack, gate-interleaved rows p=(n%HU)*4+n/HU
__global__ void pack_f16(const float* __restrict__ src, int total, int K, int Kp,
                         int coff, int HU, f16* __restrict__ dh)
{
    int idx = blockIdx.x * blockDim.x + threadIdx.x;
    if (idx >= total) return;
    int n = idx / K, k = idx - n * K;
    int p = (n % HU) * 4 + n / HU;
    dh[(size_t)p * Kp + coff + k] = (f16)src[idx];
}

// flat fp32 -> fp16
__global__ void pack_flat_f16(const float* __restrict__ src, int total, f16* __restrict__ d)
{
    int idx = blockIdx.x * blockDim.x + threadIdx.x;
    if (idx < total) d[idx] = (f16)src[idx];
}

// l3 weights -> f16 [70][200] k-major
__global__ void pack_l3(const float* __restrict__ wih, const float* __restrict__ whh,
                        f16* __restrict__ W3p)
{
    int idx = blockIdx.x * blockDim.x + threadIdx.x;
    if (idx >= 70 * 200) return;
    int k = idx / 200, n = idx - k * 200;
    float v = (k < 20) ? wih[n * 20 + k] : whh[n * 50 + (k - 20)];
    W3p[idx] = (f16)v;
}

// permuted combined bias: bp[u*4+g] = bih[g*H+u] + bhh[g*H+u]
__global__ void bias_pack(const float* __restrict__ bih, const float* __restrict__ bhh,
                          int H, float* __restrict__ bp)
{
    int idx = blockIdx.x * blockDim.x + threadIdx.x;
    if (idx >= 4 * H) return;
    int g = idx / H, u = idx - g * H;
    bp[u * 4 + g] = bih[idx] + bhh[idx];
}

// plain bias sum
__global__ void bias_sum(const float* __restrict__ a, const float* __restrict__ b,
                         int n, float* __restrict__ d)
{
    int idx = blockIdx.x * blockDim.x + threadIdx.x;
    if (idx < n) d[idx] = a[idx] + b[idx];
}

// ---------------------------------------------------------------------------
// encoder recurrences
// ---------------------------------------------------------------------------
__global__ __launch_bounds__(256)
void enc_rec1(const float* __restrict__ xp, int T,
              const float* __restrict__ whh,           // [240][60]
              float* __restrict__ hbuf, float* __restrict__ cbuf,
              unsigned short* __restrict__ h1h, unsigned short* __restrict__ h1l)
{
    __shared__ float Wt[60][240];
    __shared__ float hs[4][60];
    for (int idx = threadIdx.x; idx < 240 * 60; idx += 256) {
        int n = idx / 60, k = idx % 60;
        Wt[k][n] = whh[idx];
    }
    int wid = threadIdx.x >> 6, lane = threadIdx.x & 63;
    int b = blockIdx.x * 4 + wid;
    float h = 0.f, c = 0.f;
    if (lane < 60) {
        h = hbuf[(size_t)b * 60 + lane];
        c = cbuf[(size_t)b * 60 + lane];
        hs[wid][lane] = h;
    }
    __syncthreads();
    for (int t = 0; t < T; ++t) {
        if (lane < 60) {
            const float* xr = xp + ((size_t)t * BATCH + b) * 240;
            float gi = xr[lane], gf = xr[60 + lane], gg = xr[120 + lane], go = xr[180 + lane];
            for (int k = 0; k < 60; ++k) {
                float v = hs[wid][k];
                gi += v * Wt[k][lane];
                gf += v * Wt[k][60 + lane];
                gg += v * Wt[k][120 + lane];
                go += v * Wt[k][180 + lane];
            }
            float cn = sigm(gf) * c + sigm(gi) * tanh_f(gg);
            float hn = sigm(go) * tanh_f(cn);
            c = cn; h = hn;
            float rh = fmaxf(hn, 0.f);
            unsigned short hh = f2bf(rh);
            size_t d = ((size_t)t * BATCH + b) * 64 + lane;
            h1h[d] = hh;
            h1l[d] = f2bf(rh - bf2f(hh));
        }
        __syncthreads();
        if (lane < 60) hs[wid][lane] = h;
        __syncthreads();
    }
    if (lane < 60) {
        hbuf[(size_t)b * 60 + lane] = h;
        cbuf[(size_t)b * 60 + lane] = c;
    }
}

__global__ __launch_bounds__(256)
void enc_rec21(const float* __restrict__ xp, int T, int t0,
               const float* __restrict__ whh,          // [80][20]
               float* __restrict__ hbuf, float* __restrict__ cbuf,
               unsigned short* __restrict__ fh, unsigned short* __restrict__ fl)
{
    __shared__ float Wt[20][80];
    __shared__ float hs[4][20];
    for (int idx = threadIdx.x; idx < 80 * 20; idx += 256) {
        int n = idx / 20, k = idx % 20;
        Wt[k][n] = whh[idx];
    }
    int wid = threadIdx.x >> 6, lane = threadIdx.x & 63;
    int b = blockIdx.x * 4 + wid;
    float h = 0.f, c = 0.f;
    if (lane < 20) {
        h = hbuf[(size_t)b * 20 + lane];
        c = cbuf[(size_t)b * 20 + lane];
        hs[wid][lane] = h;
    }
    __syncthreads();
    for (int t = 0; t < T; ++t) {
        if (lane < 20) {
            const float* xr = xp + ((size_t)t * BATCH + b) * 80;
            float gi = xr[lane], gf = xr[20 + lane], gg = xr[40 + lane], go = xr[60 + lane];
            for (int k = 0; k < 20; ++k) {
                float v = hs[wid][k];
                gi += v * Wt[k][lane];
                gf += v * Wt[k][20 + lane];
                gg += v * Wt[k][40 + lane];
                go += v * Wt[k][60 + lane];
            }
            float cn = sigm(gf) * c + sigm(gi) * tanh_f(gg);
            float hn = sigm(go) * tanh_f(cn);
            c = cn; h = hn;
            int col = (t0 + t) * 20 + lane;
            unsigned short hh = f2bf(hn);
            fh[(size_t)b * KPL1 + col] = hh;
            fl[(size_t)b * KPL1 + col] = f2bf(hn - bf2f(hh));
        }
        __syncthreads();
        if (lane < 20) hs[wid][lane] = h;
        __syncthreads();
    }
    if (lane < 20) {
        hbuf[(size_t)b * 20 + lane] = h;
        cbuf[(size_t)b * 20 + lane] = c;
    }
}

// ---------------------------------------------------------------------------
// decoder l3 cell for t=0
// ---------------------------------------------------------------------------
__global__ __launch_bounds__(256)
void dec_l3(const float* __restrict__ outb,
            const float* __restrict__ wih,
            const float* __restrict__ whh,
            const float* __restrict__ bih, const float* __restrict__ bhh,
            float* __restrict__ h_t, float* __restrict__ c_t,
            f16* __restrict__ a4)
{
    __shared__ float Wt[70][200];
    __shared__ float xin[4][70];
    for (int idx = threadIdx.x; idx < 200 * 20; idx += 256) {
        int n = idx / 20, k = idx % 20;
        Wt[k][n] = wih[idx];
    }
    for (int idx = threadIdx.x; idx < 200 * 50; idx += 256) {
        int n = idx / 50, k = idx % 50;
        Wt[20 + k][n] = whh[idx];
    }
    int wid = threadIdx.x >> 6, lane = threadIdx.x & 63;
    int b = blockIdx.x * 4 + wid;
    if (lane < 20) xin[wid][lane]      = outb[(size_t)b * 20 + lane];
    if (lane < 50) xin[wid][20 + lane] = h_t[(size_t)b * 50 + lane];
    __syncthreads();
    if (lane < 50) {
        float gi = bih[lane] + bhh[lane];
        float gf = bih[50 + lane] + bhh[50 + lane];
        float gg = bih[100 + lane] + bhh[100 + lane];
        float go = bih[150 + lane] + bhh[150 + lane];
        for (int k = 0; k < 70; ++k) {
            float v = xin[wid][k];
            gi += v * Wt[k][lane];
            gf += v * Wt[k][50 + lane];
            gg += v * Wt[k][100 + lane];
            go += v * Wt[k][150 + lane];
        }
        float cold = c_t[(size_t)b * 50 + lane];
        float cn = sigm(gf) * cold + sigm(gi) * tanh_f(gg);
        float hn = sigm(go) * tanh_f(cn);
        c_t[(size_t)b * 50 + lane] = cn;
        h_t[(size_t)b * 50 + lane] = hn;
        a4[(size_t)b * KP4 + lane] = (f16)hn;
    }
}

// ---------------------------------------------------------------------------
// fused down2 + l3 cell for t>=1: wave-per-row, 8 rows per block, 256 blocks
// ---------------------------------------------------------------------------
__global__ __launch_bounds__(512)
void dec_step3(const float* __restrict__ h3prev,
               const f16* __restrict__ w2p, const float* __restrict__ b2,
               const f16* __restrict__ W3p,
               const float* __restrict__ bih, const float* __restrict__ bhh,
               float* __restrict__ h_t, float* __restrict__ c_t,
               f16* __restrict__ a4)
{
    __shared__ f16   w2s[20][512];
    __shared__ f16   W3s[70 * 200];
    __shared__ float xb[8][80];
    const int tid  = threadIdx.x;
    const int lane = tid & 63;
    const int w    = tid >> 6;
    const int row  = blockIdx.x * 8 + w;

    for (int idx = tid; idx < 20 * 512; idx += 512)
        w2s[idx >> 9][idx & 511] = w2p[idx];
    for (int idx = tid; idx < 70 * 200; idx += 512)
        W3s[idx] = W3p[idx];
    if (lane < 50) xb[w][20 + lane] = h_t[(size_t)row * 50 + lane];

    float hreg[8];
    const float* hrow = h3prev + (size_t)row * 512;
    #pragma unroll
    for (int c = 0; c < 8; ++c) hreg[c] = hrow[lane + 64 * c];
    __syncthreads();

    #pragma unroll 4
    for (int n = 0; n < 20; ++n) {
        float s = 0.f;
        #pragma unroll
        for (int c = 0; c < 8; ++c) s += hreg[c] * (float)w2s[n][lane + 64 * c];
        #pragma unroll
        for (int o = 32; o; o >>= 1) s += __shfl_xor(s, o);
        if (lane == 0) xb[w][n] = s + b2[n];
    }
    __syncthreads();

    if (lane < 50) {
        const int u = lane;
        float gi = bih[u] + bhh[u];
        float gf = bih[50 + u] + bhh[50 + u];
        float gg = bih[100 + u] + bhh[100 + u];
        float go = bih[150 + u] + bhh[150 + u];
        for (int k = 0; k < 70; ++k) {
            float v = xb[w][k];
            const f16* wk = W3s + k * 200;
            gi += v * (float)wk[u];
            gf += v * (float)wk[50 + u];
            gg += v * (float)wk[100 + u];
            go += v * (float)wk[150 + u];
        }
        size_t ci = (size_t)row * 50 + u;
        float cn = sigm(gf) * c_t[ci] + sigm(gi) * tanh_f(gg);
        float hn = sigm(go) * tanh_f(cn);
        c_t[ci] = cn;
        h_t[ci] = hn;
        a4[(size_t)row * KP4 + u] = (f16)hn;
    }
}

// ---------------------------------------------------------------------------
extern "C" void kernel_launch(void* const* d_in, const int* in_sizes, int n_in,
                              void* d_out_v, int out_size, void* d_ws, size_t ws_size,
                              hipStream_t stream)
{
    const float* x        = (const float*)d_in[0];
    const float* fc1_wih  = (const float*)d_in[1];
    const float* fc1_whh  = (const float*)d_in[2];
    const float* fc1_bih  = (const float*)d_in[3];
    const float* fc1_bhh  = (const float*)d_in[4];
    const float* fc21_wih = (const float*)d_in[5];
    const float* fc21_whh = (const float*)d_in[6];
    const float* fc21_bih = (const float*)d_in[7];
    const float* fc21_bhh = (const float*)d_in[8];
    const float* lin1_w   = (const float*)d_in[9];
    const float* lin1_b   = (const float*)d_in[10];
    const float* lin2_w   = (const float*)d_in[11];
    const float* lin2_b   = (const float*)d_in[12];
    const float* idlin_w  = (const float*)d_in[13];
    const float* idlin_b  = (const float*)d_in[14];
    const float* down1_w  = (const float*)d_in[15];
    const float* down1_b  = (const float*)d_in[16];
    const float* down2_w  = (const float*)d_in[17];
    const float* down2_b  = (const float*)d_in[18];
    const float* l3_wih   = (const float*)d_in[19];
    const float* l3_whh   = (const float*)d_in[20];
    const float* l3_bih   = (const float*)d_in[21];
    const float* l3_bhh   = (const float*)d_in[22];
    const float* l4_wih   = (const float*)d_in[23];
    const float* l4_whh   = (const float*)d_in[24];
    const float* l4_bih   = (const float*)d_in[25];
    const float* l4_bhh   = (const float*)d_in[26];
    const float* l5_wih   = (const float*)d_in[27];
    const float* l5_whh   = (const float*)d_in[28];
    const float* l5_bih   = (const float*)d_in[29];
    const float* l5_bhh   = (const float*)d_in[30];
    float* out = (float*)d_out_v;

    char* base = (char*)d_ws;
    size_t off = 0;
    auto alloc = [&](size_t bytes) -> void* {
        off = (off + 255) & ~(size_t)255;
        void* p = base + off;
        off += bytes;
        return p;
    };

    // --- zero-init 16-bit region ---
    size_t us_begin = (off + 255) & ~(size_t)255;
    f16* W4h = (f16*)alloc((size_t)3200 * KP4 * 2);
    f16* W5h = (f16*)alloc((size_t)2048 * KP5 * 2);
    unsigned short* L1h = (unsigned short*)alloc((size_t)896 * KPL1 * 2);
    unsigned short* L1l = (unsigned short*)alloc((size_t)896 * KPL1 * 2);
    unsigned short* Fh  = (unsigned short*)alloc((size_t)BATCH * KPL1 * 2);
    unsigned short* Fl  = (unsigned short*)alloc((size_t)BATCH * KPL1 * 2);
    unsigned short* Fc1h  = (unsigned short*)alloc((size_t)256 * 64 * 2);
    unsigned short* Fc1l  = (unsigned short*)alloc((size_t)256 * 64 * 2);
    unsigned short* Fc21h = (unsigned short*)alloc((size_t)128 * 64 * 2);
    unsigned short* Fc21l = (unsigned short*)alloc((size_t)128 * 64 * 2);
    const int CH = 20;
    unsigned short* H1h = (unsigned short*)alloc((size_t)CH * BATCH * 64 * 2);
    unsigned short* H1l = (unsigned short*)alloc((size_t)CH * BATCH * 64 * 2);
    f16* A4[2]; f16* A5[2];
    for (int p = 0; p < 2; ++p) {
        A4[p] = (f16*)alloc((size_t)BATCH * KP4 * 2);
        A5[p] = (f16*)alloc((size_t)BATCH * KP5 * 2);
    }
    size_t us_end = off;

    // --- zero-init fp32 region ---
    size_t fz_begin = (off + 255) & ~(size_t)255;
    float* c2   = (float*)alloc((size_t)BATCH * MID_O * 4);
    float* c3   = (float*)alloc((size_t)BATCH * OUT_DIM * 4);
    float* hb1  = (float*)alloc((size_t)BATCH * MID_I * 4);
    float* cb1  = (float*)alloc((size_t)BATCH * MID_I * 4);
    float* hb21 = (float*)alloc((size_t)BATCH * LATENT * 4);
    float* cb21 = (float*)alloc((size_t)BATCH * LATENT * 4);
    size_t fz_end = off;

    // --- no-init buffers ---
    float* bp4   = (float*)alloc((size_t)4 * MID_O * 4);
    float* bp5   = (float*)alloc((size_t)4 * OUT_DIM * 4);
    float* bs1   = (float*)alloc((size_t)4 * MID_I * 4);
    float* bs21  = (float*)alloc((size_t)4 * LATENT * 4);
    f16*   w2p   = (f16*)alloc((size_t)LATENT * OUT_DIM * 2);
    f16*   W3p   = (f16*)alloc((size_t)70 * 200 * 2);
    float* mu1   = (float*)alloc((size_t)BATCH * V_MID * 4);
    float* mu    = (float*)alloc((size_t)BATCH * V_LAT * 4);
    float* h_t   = (float*)alloc((size_t)BATCH * V_LAT * 4);
    float* c_t   = (float*)alloc((size_t)BATCH * V_LAT * 4);
    float* outb  = (float*)alloc((size_t)BATCH * LATENT * 4);
    unsigned short* Xh = (unsigned short*)alloc((size_t)SEQ * BATCH * 64 * 2);
    unsigned short* Xl = (unsigned short*)alloc((size_t)SEQ * BATCH * 64 * 2);
    float* xp1c  = (float*)alloc((size_t)CH * BATCH * 4 * MID_I * 4);
    float* xp21c = (float*)alloc((size_t)CH * BATCH * 4 * LATENT * 4);

    hipMemsetAsync(base + us_begin, 0, us_end - us_begin, stream);
    hipMemsetAsync(base + fz_begin, 0, fz_end - fz_begin, stream);

    // --- weight/bias packing ---
    pack_f16<<<(3200 * 50  + 255) / 256, 256, 0, stream>>>(l4_wih, 3200 * 50,  50,  KP4, 0,   800, W4h);
    pack_f16<<<(3200 * 800 + 255) / 256, 256, 0, stream>>>(l4_whh, 3200 * 800, 800, KP4, 64,  800, W4h);
    pack_f16<<<(2048 * 800 + 255) / 256, 256, 0, stream>>>(l5_wih, 2048 * 800, 800, KP5, 0,   512, W5h);
    pack_f16<<<(2048 * 512 + 255) / 256, 256, 0, stream>>>(l5_whh, 2048 * 512, 512, KP5, 832, 512, W5h);
    split_pack_lin1<<<(V_MID * LATENT * SEQ + 255) / 256, 256, 0, stream>>>(lin1_w, L1h, L1l);
    split_pack_rows<<<(240 * 64 + 255) / 256, 256, 0, stream>>>(fc1_wih, 240 * 64, 64, 64, Fc1h, Fc1l);
    split_pack_rows<<<(80 * 60 + 255) / 256, 256, 0, stream>>>(fc21_wih, 80 * 60, 60, 64, Fc21h, Fc21l);
    split_pack_rows<<<(SEQ * BATCH * 64 + 255) / 256, 256, 0, stream>>>(x, SEQ * BATCH * 64, 64, 64, Xh, Xl);
    pack_flat_f16<<<(LATENT * OUT_DIM + 255) / 256, 256, 0, stream>>>(down2_w, LATENT * OUT_DIM, w2p);
    pack_l3<<<(70 * 200 + 255) / 256, 256, 0, stream>>>(l3_wih, l3_whh, W3p);
    bias_pack<<<(4 * MID_O   + 255) / 256, 256, 0, stream>>>(l4_bih, l4_bhh, MID_O,   bp4);
    bias_pack<<<(4 * OUT_DIM + 255) / 256, 256, 0, stream>>>(l5_bih, l5_bhh, OUT_DIM, bp5);
    bias_sum<<<1, 256, 0, stream>>>(fc1_bih, fc1_bhh, 4 * MID_I, bs1);
    bias_sum<<<1, 256, 0, stream>>>(fc21_bih, fc21_bhh, 4 * LATENT, bs21);

    // ---------------- encoder ----------------
    for (int c0 = 0; c0 < SEQ; c0 += CH) {
        {
            dim3 g(2, CH * BATCH / 128);
            gemm_mfma0<false><<<g, 256, 0, stream>>>(
                Xh + (size_t)c0 * BATCH * 64, Xl + (size_t)c0 * BATCH * 64,
                Fc1h, Fc1l, 64, 4 * MID_I, bs1, xp1c);
        }
        enc_rec1<<<BATCH / 4, 256, 0, stream>>>(xp1c, CH, fc1_whh, hb1, cb1, H1h, H1l);
        {
            dim3 g(1, CH * BATCH / 128);
            gemm_mfma0<false><<<g, 256, 0, stream>>>(
                H1h, H1l, Fc21h, Fc21l, 64, 4 * LATENT, bs21, xp21c);
        }
        enc_rec21<<<BATCH / 4, 256, 0, stream>>>(xp21c, CH, c0, fc21_whh, hb21, cb21, Fh, Fl);
    }

    // lin1 (bf16 3-term MFMA) + lin2 (fp32)
    {
        dim3 g(7, 16);
        gemm_mfma0<true><<<g, 256, 0, stream>>>(Fh, Fl, L1h, L1l, KPL1, V_MID, lin1_b, mu1);
    }
    {
        dim3 g((V_LAT + BN - 1) / BN, BATCH / BM);
        gemm2k<false, true><<<g, 256, 0, stream>>>(mu1, V_MID, nullptr, 0,
            lin2_w, nullptr, lin2_b, nullptr, mu, BATCH, V_LAT);
    }

    // ---------------- decoder init ----------------
    hipMemcpyAsync(h_t, mu, (size_t)BATCH * V_LAT * 4, hipMemcpyDeviceToDevice, stream);
    {
        dim3 g(1, BATCH / BM);
        gemm2k<false, false><<<g, 256, 0, stream>>>(mu, V_LAT, nullptr, 0,
            idlin_w, nullptr, idlin_b, nullptr, c_t, BATCH, V_LAT);
        gemm2k<false, false><<<g, 256, 0, stream>>>(mu, V_LAT, nullptr, 0,
            down1_w, nullptr, down1_b, nullptr, outb, BATCH, LATENT);
    }

    // ---------------- decoder scan ----------------
    for (int t = 0; t < SEQ; ++t) {
        const int p = t & 1;
        if (t == 0) {
            dec_l3<<<BATCH / 4, 256, 0, stream>>>(outb, l3_wih, l3_whh, l3_bih, l3_bhh,
                                                  h_t, c_t, A4[0]);
        } else {
            dec_step3<<<BATCH / 8, 512, 0, stream>>>(
                out + (size_t)(t - 1) * BATCH * OUT_DIM,
                w2p, down2_b, W3p, l3_bih, l3_bhh,
                h_t, c_t, A4[p]);
        }
        {
            // l4: 25 col x 16 row tiles = 400 blocks; each XCD owns 2 row-tiles
            gemm_dec<1><<<dim3(400), 256, 0, stream>>>(
                A4[p], W4h, KP4, KP4 / 32, MID_O, 2, bp4, c2,
                A4[p ^ 1], KP4, 64,
                A5[p], KP5, 0,
                nullptr);
        }
        {
            // l5: 16 col x 16 row tiles = 256 blocks; each XCD owns 2 row-tiles
            gemm_dec<2><<<dim3(256), 256, 0, stream>>>(
                A5[p], W5h, KP5, KP5 / 32, OUT_DIM, 2, bp5, c3,
                A5[p ^ 1], KP5, 832,
                nullptr, 0, 0,
                out + (size_t)t * BATCH * OUT_DIM);
        }
    }

    hipMemcpyAsync(out + (size_t)SEQ * BATCH * OUT_DIM, mu,
                   (size_t)BATCH * V_LAT * 4, hipMemcpyDeviceToDevice, stream);
}

// Round 13
// 7539.042 us; speedup vs baseline: 1.0092x; 1.0092x over previous
//
#include <hip/hip_runtime.h>
#include <cstdint>
#include <cstddef>

#define SEQ     100
#define BATCH   2048
#define IN_DIM  64
#define MID_I   60
#define LATENT  20
#define V_MID   800
#define V_LAT   50
#define MID_O   800
#define OUT_DIM 512

#define KP4  896    // [h_t pad 64 | h2 800 | pad to 896]
#define KP5  1344   // [h2 800 pad 832 | h3 512]
#define KPL1 2048   // latent*seq 2000 padded

using f32x4  = __attribute__((ext_vector_type(4))) float;
using u16x8  = __attribute__((ext_vector_type(8))) unsigned short;
using bf16x8 = __attribute__((ext_vector_type(8))) __bf16;
typedef _Float16 f16;
typedef _Float16 f16x8 __attribute__((ext_vector_type(8)));

__device__ __forceinline__ unsigned short f2bf(float x){
    unsigned u = __builtin_bit_cast(unsigned, x);
    u += 0x7FFFu + ((u >> 16) & 1u);
    return (unsigned short)(u >> 16);
}
__device__ __forceinline__ float bf2f(unsigned short b){
    unsigned u = ((unsigned)b) << 16; return __builtin_bit_cast(float, u);
}
__device__ __forceinline__ float sigm(float x){ return 1.f/(1.f+__expf(-x)); }
__device__ __forceinline__ float tanh_f(float x){ return 1.f - 2.f/(__expf(2.f*x)+1.f); }

typedef const __attribute__((address_space(1))) unsigned int* gas_ptr;
typedef __attribute__((address_space(3))) unsigned int* las_ptr;
__device__ __forceinline__ void gld16(const void* g, char* l) {
    __builtin_amdgcn_global_load_lds((gas_ptr)g, (las_ptr)l, 16, 0, 0);
}

// ---------------------------------------------------------------------------
// fp32 tiled GEMM (lin2, decoder init only)
// ---------------------------------------------------------------------------
constexpr int BM = 64, BN = 64, BK = 16;
template<bool RELU_A1, bool RELU_OUT>
__global__ __launch_bounds__(256)
void gemm2k(const float* __restrict__ A1, int K1,
            const float* __restrict__ A2, int K2,
            const float* __restrict__ W1, const float* __restrict__ W2,
            const float* __restrict__ b1, const float* __restrict__ b2,
            float* __restrict__ C, int M, int N)
{
    __shared__ float As[BK][BM + 1];
    __shared__ float Bs[BK][BN + 1];
    const int tx = threadIdx.x & 15;
    const int ty = threadIdx.x >> 4;
    const int n0 = blockIdx.x * BN;
    const int m0 = blockIdx.y * BM;

    float acc[4][4] = {};

    for (int src = 0; src < 2; ++src) {
        const float* A = src ? A2 : A1;
        const float* W = src ? W2 : W1;
        const int    K = src ? K2 : K1;
        if (A == nullptr || K == 0) continue;
        for (int k0 = 0; k0 < K; k0 += BK) {
            #pragma unroll
            for (int i = 0; i < 4; ++i) {
                int idx = threadIdx.x + i * 256;
                int k = idx & 15, m = idx >> 4;
                int gm = m0 + m, gk = k0 + k;
                float v = 0.f;
                if (gm < M && gk < K) v = A[(size_t)gm * K + gk];
                if (RELU_A1 && src == 0) v = fmaxf(v, 0.f);
                As[k][m] = v;
            }
            #pragma unroll
            for (int i = 0; i < 4; ++i) {
                int idx = threadIdx.x + i * 256;
                int k = idx & 15, n = idx >> 4;
                int gn = n0 + n, gk = k0 + k;
                float v = 0.f;
                if (gn < N && gk < K) v = W[(size_t)gn * K + gk];
                Bs[k][n] = v;
            }
            __syncthreads();
            #pragma unroll
            for (int kk = 0; kk < BK; ++kk) {
                float a[4], b[4];
                #pragma unroll
                for (int i = 0; i < 4; ++i) a[i] = As[kk][ty + i * 16];
                #pragma unroll
                for (int j = 0; j < 4; ++j) b[j] = Bs[kk][tx + j * 16];
                #pragma unroll
                for (int i = 0; i < 4; ++i)
                    #pragma unroll
                    for (int j = 0; j < 4; ++j)
                        acc[i][j] += a[i] * b[j];
            }
            __syncthreads();
        }
    }

    #pragma unroll
    for (int i = 0; i < 4; ++i) {
        int gm = m0 + ty + i * 16;
        if (gm >= M) continue;
        #pragma unroll
        for (int j = 0; j < 4; ++j) {
            int gn = n0 + tx + j * 16;
            if (gn >= N) continue;
            float v = acc[i][j];
            if (b1) v += b1[gn];
            if (b2) v += b2[gn];
            if (RELU_OUT) v = fmaxf(v, 0.f);
            C[(size_t)gm * N + gn] = v;
        }
    }
}

// ---------------------------------------------------------------------------
// split-bf16 3-term MFMA GEMM, 128x128 tile, plain fp32 store (+opt relu).
// Used for lin1 and the encoder projections.
// ---------------------------------------------------------------------------
template<bool RELU>
__global__ __launch_bounds__(256, 2)
void gemm_mfma0(const unsigned short* __restrict__ Ah, const unsigned short* __restrict__ Al,
                const unsigned short* __restrict__ Bh, const unsigned short* __restrict__ Bl,
                int Kp, int Nstore, const float* __restrict__ bi, float* __restrict__ Cout)
{
    __shared__ __align__(16) char smem[32768];
    const int tid  = threadIdx.x;
    const int lane = tid & 63;
    const int wid  = tid >> 6;
    const int m0   = blockIdx.y * 128;
    const int n0   = blockIdx.x * 128;
    const int wr   = (wid >> 1) << 6;
    const int wc   = (wid & 1) << 6;
    const int fr   = lane & 15;
    const int fg   = lane >> 4;
    const int slotR = ((fg ^ (fr & 3)) << 4);

    const int r0 = 32 * wid + (lane >> 2);
    const int sl = (((lane & 3) ^ ((lane >> 2) & 3)) << 3);
    const unsigned short* gA0h = Ah + (size_t)(m0 + r0)      * Kp + sl;
    const unsigned short* gA1h = Ah + (size_t)(m0 + r0 + 16) * Kp + sl;
    const unsigned short* gA0l = Al + (size_t)(m0 + r0)      * Kp + sl;
    const unsigned short* gA1l = Al + (size_t)(m0 + r0 + 16) * Kp + sl;
    const unsigned short* gB0h = Bh + (size_t)(n0 + r0)      * Kp + sl;
    const unsigned short* gB1h = Bh + (size_t)(n0 + r0 + 16) * Kp + sl;
    const unsigned short* gB0l = Bl + (size_t)(n0 + r0)      * Kp + sl;
    const unsigned short* gB1l = Bl + (size_t)(n0 + r0 + 16) * Kp + sl;
    char* lA0h = smem +     0 + (2 * wid    ) * 1024;
    char* lA1h = smem +     0 + (2 * wid + 1) * 1024;
    char* lA0l = smem +  8192 + (2 * wid    ) * 1024;
    char* lA1l = smem +  8192 + (2 * wid + 1) * 1024;
    char* lB0h = smem + 16384 + (2 * wid    ) * 1024;
    char* lB1h = smem + 16384 + (2 * wid + 1) * 1024;
    char* lB0l = smem + 24576 + (2 * wid    ) * 1024;
    char* lB1l = smem + 24576 + (2 * wid + 1) * 1024;

    f32x4 acc[4][4];
    #pragma unroll
    for (int i = 0; i < 4; ++i)
        #pragma unroll
        for (int j = 0; j < 4; ++j) acc[i][j] = (f32x4){0.f, 0.f, 0.f, 0.f};

    for (int k0 = 0; k0 < Kp; k0 += 32) {
        __syncthreads();
        gld16(gA0h + k0, lA0h); gld16(gA1h + k0, lA1h);
        gld16(gA0l + k0, lA0l); gld16(gA1l + k0, lA1l);
        gld16(gB0h + k0, lB0h); gld16(gB1h + k0, lB1h);
        gld16(gB0l + k0, lB0l); gld16(gB1l + k0, lB1l);
        __syncthreads();

        bf16x8 ah[4], al[4];
        #pragma unroll
        for (int i = 0; i < 4; ++i) {
            int ro = (wr + i * 16 + fr) * 64 + slotR;
            ah[i] = *(const bf16x8*)(smem +        ro);
            al[i] = *(const bf16x8*)(smem + 8192 + ro);
        }
        #pragma unroll
        for (int j = 0; j < 4; ++j) {
            int ro = (wc + j * 16 + fr) * 64 + slotR;
            bf16x8 fbh = *(const bf16x8*)(smem + 16384 + ro);
            bf16x8 fbl = *(const bf16x8*)(smem + 24576 + ro);
            #pragma unroll
            for (int i = 0; i < 4; ++i) {
                acc[i][j] = __builtin_amdgcn_mfma_f32_16x16x32_bf16(ah[i], fbh, acc[i][j], 0, 0, 0);
                acc[i][j] = __builtin_amdgcn_mfma_f32_16x16x32_bf16(ah[i], fbl, acc[i][j], 0, 0, 0);
                acc[i][j] = __builtin_amdgcn_mfma_f32_16x16x32_bf16(al[i], fbh, acc[i][j], 0, 0, 0);
            }
        }
    }

    #pragma unroll
    for (int j = 0; j < 4; ++j) {
        int gc = n0 + wc + j * 16 + fr;
        if (gc >= Nstore) continue;
        float badd = bi[gc];
        #pragma unroll
        for (int i = 0; i < 4; ++i)
            #pragma unroll
            for (int r = 0; r < 4; ++r) {
                int gr = m0 + wr + i * 16 + fg * 4 + r;
                float v = acc[i][j][r] + badd;
                if (RELU) v = fmaxf(v, 0.f);
                Cout[(size_t)gr * Nstore + gc] = v;
            }
    }
}

// ---------------------------------------------------------------------------
// decoder GEMM: fp16 MFMA, 128x128 tile, 4 waves, 3-buffer counted-vmcnt
// pipeline, LDS-transposed coalesced LSTM epilogue.
// XCD chunking over ROWS: xcd owns NBYX row-tiles (A stays L2-resident),
// weights stream through once per XCD.
// Grid = NBX*NBYX*8 blocks. MODE 1 = l4, MODE 2 = l5.
// ---------------------------------------------------------------------------
template<int MODE>
__global__ __launch_bounds__(256, 3)
void gemm_dec(const f16* __restrict__ A, const f16* __restrict__ W,
              int Kp, int NK, int H, int NBYX,
              const float* __restrict__ bp,     // permuted combined bias [H*4]
              float* __restrict__ cstate,
              f16* __restrict__ wr1, int st1, int off1,
              f16* __restrict__ wr2, int st2, int off2,
              float* __restrict__ out_t)
{
    __shared__ __align__(16) char smem[49152];   // 3 buffers x (A 8K + W 8K)
    const int xcd = blockIdx.x & 7;
    const int ii  = blockIdx.x >> 3;
    const int by  = xcd * NBYX + (ii % NBYX);    // row-tile: L2-resident per XCD
    const int bx  = ii / NBYX;                   // col-tile: streamed
    const int m0 = by * 128;
    const int n0 = bx * 128;

    const int tid  = threadIdx.x;
    const int lane = tid & 63;
    const int wid  = tid >> 6;         // 0..3
    const int wm   = wid >> 1;         // 0..1
    const int wn   = wid & 1;          // 0..1
    const int fr   = lane & 15;
    const int fg   = lane >> 4;
    const int swz  = (fg ^ (fr & 3) ^ ((fr >> 2) & 1)) * 16;

    const int rbase = 32 * wid;
    const int lrow  = lane >> 2;
    const int chnk  = (lane & 3) ^ ((lane >> 2) & 3) ^ ((lane >> 4) & 1);
    const f16* sA0 = A + (size_t)(m0 + rbase + lrow)      * Kp + chnk * 8;
    const f16* sA1 = A + (size_t)(m0 + rbase + 16 + lrow) * Kp + chnk * 8;
    const f16* sW0 = W + (size_t)(n0 + rbase + lrow)      * Kp + chnk * 8;
    const f16* sW1 = W + (size_t)(n0 + rbase + 16 + lrow) * Kp + chnk * 8;

    f32x4 acc[4][4];
    #pragma unroll
    for (int i = 0; i < 4; ++i)
        #pragma unroll
        for (int j = 0; j < 4; ++j) acc[i][j] = (f32x4){0.f, 0.f, 0.f, 0.f};

    auto stage = [&](int t, int buf) {
        const int kb = t * 32;
        char* bb = smem + buf * 16384;
        gld16(sA0 + kb, bb + rbase * 64);
        gld16(sA1 + kb, bb + (rbase + 16) * 64);
        gld16(sW0 + kb, bb + 8192 + rbase * 64);
        gld16(sW1 + kb, bb + 8192 + (rbase + 16) * 64);
    };

    stage(0, 0);
    stage(1, 1);

    int buf = 0;
    for (int t = 0; t < NK; ++t) {
        if (t + 1 < NK) asm volatile("s_waitcnt vmcnt(4)" ::: "memory");
        else            asm volatile("s_waitcnt vmcnt(0)" ::: "memory");
        __builtin_amdgcn_s_barrier();
        if (t + 2 < NK) stage(t + 2, (buf + 2) % 3);
        const char* bb = smem + buf * 16384;
        f16x8 af[4];
        #pragma unroll
        for (int i = 0; i < 4; ++i)
            af[i] = *(const f16x8*)(bb + (64 * wm + 16 * i + fr) * 64 + swz);
        #pragma unroll
        for (int j = 0; j < 4; ++j) {
            f16x8 vw = *(const f16x8*)(bb + 8192 + (64 * wn + 16 * j + fr) * 64 + swz);
            #pragma unroll
            for (int i = 0; i < 4; ++i)
                acc[i][j] = __builtin_amdgcn_mfma_f32_16x16x32_f16(af[i], vw, acc[i][j], 0, 0, 0);
        }
        buf = (buf + 1) % 3;
    }

    // -------- epilogue: LDS gate transpose -> coalesced LSTM pointwise ----
    float* gt = (float*)smem;              // [64][132]
    const int u32 = tid & 31;              // unit within tile
    const int r8  = tid >> 5;              // 0..7
    const int unit = (n0 >> 2) + u32;
    const f32x4 bv = ((const f32x4*)bp)[unit];

    #pragma unroll
    for (int half = 0; half < 2; ++half) {
        __syncthreads();
        if (wm == half) {
            #pragma unroll
            for (int i = 0; i < 4; ++i)
                #pragma unroll
                for (int j = 0; j < 4; ++j)
                    #pragma unroll
                    for (int r = 0; r < 4; ++r)
                        gt[(16*i + 4*fg + r) * 132 + 64*wn + 16*j + fr] = acc[i][j][r];
        }
        __syncthreads();
        #pragma unroll
        for (int kk = 0; kk < 8; ++kk) {
            const int lr  = 8 * kk + r8;
            const int row = m0 + 64 * half + lr;
            f32x4 g = *(const f32x4*)(gt + lr * 132 + u32 * 4);
            float gi = g[0] + bv[0], gf = g[1] + bv[1];
            float gg = g[2] + bv[2], go = g[3] + bv[3];
            size_t ci = (size_t)row * H + unit;
            float cn = sigm(gf) * cstate[ci] + sigm(gi) * tanh_f(gg);
            float hn = sigm(go) * tanh_f(cn);
            cstate[ci] = cn;
            f16 hh = (f16)hn;
            wr1[(size_t)row * st1 + off1 + unit] = hh;
            if (MODE == 1) wr2[(size_t)row * st2 + off2 + unit] = hh;
            if (MODE == 2) out_t[(size_t)row * H + unit] = hn;
        }
    }
}

// ---------------------------------------------------------------------------
// packing kernels
// ---------------------------------------------------------------------------
__global__ void split_pack_lin1(const float* __restrict__ src,
                                unsigned short* __restrict__ dh, unsigned short* __restrict__ dl)
{
    int idx = blockIdx.x * blockDim.x + threadIdx.x;
    if (idx >= V_MID * LATENT * SEQ) return;
    int n = idx / (LATENT * SEQ), c = idx - n * (LATENT * SEQ);
    int l = c / SEQ, s = c - l * SEQ;
    float x = src[idx];
    unsigned short h = f2bf(x);
    size_t d = (size_t)n * KPL1 + s * LATENT + l;
    dh[d] = h;
    dl[d] = f2bf(x - bf2f(h));
}

// generic fp32 -> bf16 hi/lo, row-major [N][K] -> [N][Kp]
__global__ void split_pack_rows(const float* __restrict__ src, int total, int K, int Kp,
                                unsigned short* __restrict__ dh, unsigned short* __restrict__ dl)
{
    int idx = blockIdx.x * blockDim.x + threadIdx.x;
    if (idx >= total) return;
    int n = idx / K, k = idx - n * K;
    float x = src[idx];
    unsigned short h = f2bf(x);
    size_t d = (size_t)n * Kp + k;
    dh[d] = h;
    dl[d] = f2bf(x - bf2f(h));
}

// fp16 weight pack, gate-interleaved rows p=(n%HU)*4+n/HU
__global__ void pack_f16(const float* __restrict__ src, int total, int K, int Kp,
                         int coff, int HU, f16* __restrict__ dh)
{
    int idx = blockIdx.x * blockDim.x + threadIdx.x;
    if (idx >= total) return;
    int n = idx / K, k = idx - n * K;
    int p = (n % HU) * 4 + n / HU;
    dh[(size_t)p * Kp + coff + k] = (f16)src[idx];
}

// flat fp32 -> fp16
__global__ void pack_flat_f16(const float* __restrict__ src, int total, f16* __restrict__ d)
{
    int idx = blockIdx.x * blockDim.x + threadIdx.x;
    if (idx < total) d[idx] = (f16)src[idx];
}

// l3 weights -> f16 [70][200] k-major
__global__ void pack_l3(const float* __restrict__ wih, const float* __restrict__ whh,
                        f16* __restrict__ W3p)
{
    int idx = blockIdx.x * blockDim.x + threadIdx.x;
    if (idx >= 70 * 200) return;
    int k = idx / 200, n = idx - k * 200;
    float v = (k < 20) ? wih[n * 20 + k] : whh[n * 50 + (k - 20)];
    W3p[idx] = (f16)v;
}

// permuted combined bias: bp[u*4+g] = bih[g*H+u] + bhh[g*H+u]
__global__ void bias_pack(const float* __restrict__ bih, const float* __restrict__ bhh,
                          int H, float* __restrict__ bp)
{
    int idx = blockIdx.x * blockDim.x + threadIdx.x;
    if (idx >= 4 * H) return;
    int g = idx / H, u = idx - g * H;
    bp[u * 4 + g] = bih[idx] + bhh[idx];
}

// plain bias sum
__global__ void bias_sum(const float* __restrict__ a, const float* __restrict__ b,
                         int n, float* __restrict__ d)
{
    int idx = blockIdx.x * blockDim.x + threadIdx.x;
    if (idx < n) d[idx] = a[idx] + b[idx];
}

// ---------------------------------------------------------------------------
// encoder recurrences
// ---------------------------------------------------------------------------
__global__ __launch_bounds__(256)
void enc_rec1(const float* __restrict__ xp, int T,
              const float* __restrict__ whh,           // [240][60]
              float* __restrict__ hbuf, float* __restrict__ cbuf,
              unsigned short* __restrict__ h1h, unsigned short* __restrict__ h1l)
{
    __shared__ float Wt[60][240];
    __shared__ float hs[4][60];
    for (int idx = threadIdx.x; idx < 240 * 60; idx += 256) {
        int n = idx / 60, k = idx % 60;
        Wt[k][n] = whh[idx];
    }
    int wid = threadIdx.x >> 6, lane = threadIdx.x & 63;
    int b = blockIdx.x * 4 + wid;
    float h = 0.f, c = 0.f;
    if (lane < 60) {
        h = hbuf[(size_t)b * 60 + lane];
        c = cbuf[(size_t)b * 60 + lane];
        hs[wid][lane] = h;
    }
    __syncthreads();
    for (int t = 0; t < T; ++t) {
        if (lane < 60) {
            const float* xr = xp + ((size_t)t * BATCH + b) * 240;
            float gi = xr[lane], gf = xr[60 + lane], gg = xr[120 + lane], go = xr[180 + lane];
            for (int k = 0; k < 60; ++k) {
                float v = hs[wid][k];
                gi += v * Wt[k][lane];
                gf += v * Wt[k][60 + lane];
                gg += v * Wt[k][120 + lane];
                go += v * Wt[k][180 + lane];
            }
            float cn = sigm(gf) * c + sigm(gi) * tanh_f(gg);
            float hn = sigm(go) * tanh_f(cn);
            c = cn; h = hn;
            float rh = fmaxf(hn, 0.f);
            unsigned short hh = f2bf(rh);
            size_t d = ((size_t)t * BATCH + b) * 64 + lane;
            h1h[d] = hh;
            h1l[d] = f2bf(rh - bf2f(hh));
        }
        __syncthreads();
        if (lane < 60) hs[wid][lane] = h;
        __syncthreads();
    }
    if (lane < 60) {
        hbuf[(size_t)b * 60 + lane] = h;
        cbuf[(size_t)b * 60 + lane] = c;
    }
}

__global__ __launch_bounds__(256)
void enc_rec21(const float* __restrict__ xp, int T, int t0,
               const float* __restrict__ whh,          // [80][20]
               float* __restrict__ hbuf, float* __restrict__ cbuf,
               unsigned short* __restrict__ fh, unsigned short* __restrict__ fl)
{
    __shared__ float Wt[20][80];
    __shared__ float hs[4][20];
    for (int idx = threadIdx.x; idx < 80 * 20; idx += 256) {
        int n = idx / 20, k = idx % 20;
        Wt[k][n] = whh[idx];
    }
    int wid = threadIdx.x >> 6, lane = threadIdx.x & 63;
    int b = blockIdx.x * 4 + wid;
    float h = 0.f, c = 0.f;
    if (lane < 20) {
        h = hbuf[(size_t)b * 20 + lane];
        c = cbuf[(size_t)b * 20 + lane];
        hs[wid][lane] = h;
    }
    __syncthreads();
    for (int t = 0; t < T; ++t) {
        if (lane < 20) {
            const float* xr = xp + ((size_t)t * BATCH + b) * 80;
            float gi = xr[lane], gf = xr[20 + lane], gg = xr[40 + lane], go = xr[60 + lane];
            for (int k = 0; k < 20; ++k) {
                float v = hs[wid][k];
                gi += v * Wt[k][lane];
                gf += v * Wt[k][20 + lane];
                gg += v * Wt[k][40 + lane];
                go += v * Wt[k][60 + lane];
            }
            float cn = sigm(gf) * c + sigm(gi) * tanh_f(gg);
            float hn = sigm(go) * tanh_f(cn);
            c = cn; h = hn;
            int col = (t0 + t) * 20 + lane;
            unsigned short hh = f2bf(hn);
            fh[(size_t)b * KPL1 + col] = hh;
            fl[(size_t)b * KPL1 + col] = f2bf(hn - bf2f(hh));
        }
        __syncthreads();
        if (lane < 20) hs[wid][lane] = h;
        __syncthreads();
    }
    if (lane < 20) {
        hbuf[(size_t)b * 20 + lane] = h;
        cbuf[(size_t)b * 20 + lane] = c;
    }
}

// ---------------------------------------------------------------------------
// decoder l3 cell for t=0
// ---------------------------------------------------------------------------
__global__ __launch_bounds__(256)
void dec_l3(const float* __restrict__ outb,
            const float* __restrict__ wih,
            const float* __restrict__ whh,
            const float* __restrict__ bih, const float* __restrict__ bhh,
            float* __restrict__ h_t, float* __restrict__ c_t,
            f16* __restrict__ a4)
{
    __shared__ float Wt[70][200];
    __shared__ float xin[4][70];
    for (int idx = threadIdx.x; idx < 200 * 20; idx += 256) {
        int n = idx / 20, k = idx % 20;
        Wt[k][n] = wih[idx];
    }
    for (int idx = threadIdx.x; idx < 200 * 50; idx += 256) {
        int n = idx / 50, k = idx % 50;
        Wt[20 + k][n] = whh[idx];
    }
    int wid = threadIdx.x >> 6, lane = threadIdx.x & 63;
    int b = blockIdx.x * 4 + wid;
    if (lane < 20) xin[wid][lane]      = outb[(size_t)b * 20 + lane];
    if (lane < 50) xin[wid][20 + lane] = h_t[(size_t)b * 50 + lane];
    __syncthreads();
    if (lane < 50) {
        float gi = bih[lane] + bhh[lane];
        float gf = bih[50 + lane] + bhh[50 + lane];
        float gg = bih[100 + lane] + bhh[100 + lane];
        float go = bih[150 + lane] + bhh[150 + lane];
        for (int k = 0; k < 70; ++k) {
            float v = xin[wid][k];
            gi += v * Wt[k][lane];
            gf += v * Wt[k][50 + lane];
            gg += v * Wt[k][100 + lane];
            go += v * Wt[k][150 + lane];
        }
        float cold = c_t[(size_t)b * 50 + lane];
        float cn = sigm(gf) * cold + sigm(gi) * tanh_f(gg);
        float hn = sigm(go) * tanh_f(cn);
        c_t[(size_t)b * 50 + lane] = cn;
        h_t[(size_t)b * 50 + lane] = hn;
        a4[(size_t)b * KP4 + lane] = (f16)hn;
    }
}

// ---------------------------------------------------------------------------
// fused down2 + l3 cell for t>=1: wave-per-row, 8 rows per block, 256 blocks
// w2 and W3 both staged as f16 (48.5 KB LDS -> 3 blocks/CU)
// ---------------------------------------------------------------------------
__global__ __launch_bounds__(512)
void dec_step3(const float* __restrict__ h3prev,
               const f16* __restrict__ w2p, const float* __restrict__ b2,
               const f16* __restrict__ W3p,
               const float* __restrict__ bih, const float* __restrict__ bhh,
               float* __restrict__ h_t, float* __restrict__ c_t,
               f16* __restrict__ a4)
{
    __shared__ f16   w2s[20][512];
    __shared__ f16   W3s[70 * 200];
    __shared__ float xb[8][80];
    const int tid  = threadIdx.x;
    const int lane = tid & 63;
    const int w    = tid >> 6;
    const int row  = blockIdx.x * 8 + w;

    for (int idx = tid; idx < 20 * 512; idx += 512)
        w2s[idx >> 9][idx & 511] = w2p[idx];
    for (int idx = tid; idx < 70 * 200; idx += 512)
        W3s[idx] = W3p[idx];
    if (lane < 50) xb[w][20 + lane] = h_t[(size_t)row * 50 + lane];

    float hreg[8];
    const float* hrow = h3prev + (size_t)row * 512;
    #pragma unroll
    for (int c = 0; c < 8; ++c) hreg[c] = hrow[lane + 64 * c];
    __syncthreads();

    #pragma unroll 4
    for (int n = 0; n < 20; ++n) {
        float s = 0.f;
        #pragma unroll
        for (int c = 0; c < 8; ++c) s += hreg[c] * (float)w2s[n][lane + 64 * c];
        #pragma unroll
        for (int o = 32; o; o >>= 1) s += __shfl_xor(s, o);
        if (lane == 0) xb[w][n] = s + b2[n];
    }
    __syncthreads();

    if (lane < 50) {
        const int u = lane;
        float gi = bih[u] + bhh[u];
        float gf = bih[50 + u] + bhh[50 + u];
        float gg = bih[100 + u] + bhh[100 + u];
        float go = bih[150 + u] + bhh[150 + u];
        for (int k = 0; k < 70; ++k) {
            float v = xb[w][k];
            const f16* wk = W3s + k * 200;
            gi += v * (float)wk[u];
            gf += v * (float)wk[50 + u];
            gg += v * (float)wk[100 + u];
            go += v * (float)wk[150 + u];
        }
        size_t ci = (size_t)row * 50 + u;
        float cn = sigm(gf) * c_t[ci] + sigm(gi) * tanh_f(gg);
        float hn = sigm(go) * tanh_f(cn);
        c_t[ci] = cn;
        h_t[ci] = hn;
        a4[(size_t)row * KP4 + u] = (f16)hn;
    }
}

// ---------------------------------------------------------------------------
extern "C" void kernel_launch(void* const* d_in, const int* in_sizes, int n_in,
                              void* d_out_v, int out_size, void* d_ws, size_t ws_size,
                              hipStream_t stream)
{
    const float* x        = (const float*)d_in[0];
    const float* fc1_wih  = (const float*)d_in[1];
    const float* fc1_whh  = (const float*)d_in[2];
    const float* fc1_bih  = (const float*)d_in[3];
    const float* fc1_bhh  = (const float*)d_in[4];
    const float* fc21_wih = (const float*)d_in[5];
    const float* fc21_whh = (const float*)d_in[6];
    const float* fc21_bih = (const float*)d_in[7];
    const float* fc21_bhh = (const float*)d_in[8];
    const float* lin1_w   = (const float*)d_in[9];
    const float* lin1_b   = (const float*)d_in[10];
    const float* lin2_w   = (const float*)d_in[11];
    const float* lin2_b   = (const float*)d_in[12];
    const float* idlin_w  = (const float*)d_in[13];
    const float* idlin_b  = (const float*)d_in[14];
    const float* down1_w  = (const float*)d_in[15];
    const float* down1_b  = (const float*)d_in[16];
    const float* down2_w  = (const float*)d_in[17];
    const float* down2_b  = (const float*)d_in[18];
    const float* l3_wih   = (const float*)d_in[19];
    const float* l3_whh   = (const float*)d_in[20];
    const float* l3_bih   = (const float*)d_in[21];
    const float* l3_bhh   = (const float*)d_in[22];
    const float* l4_wih   = (const float*)d_in[23];
    const float* l4_whh   = (const float*)d_in[24];
    const float* l4_bih   = (const float*)d_in[25];
    const float* l4_bhh   = (const float*)d_in[26];
    const float* l5_wih   = (const float*)d_in[27];
    const float* l5_whh   = (const float*)d_in[28];
    const float* l5_bih   = (const float*)d_in[29];
    const float* l5_bhh   = (const float*)d_in[30];
    float* out = (float*)d_out_v;

    char* base = (char*)d_ws;
    size_t off = 0;
    auto alloc = [&](size_t bytes) -> void* {
        off = (off + 255) & ~(size_t)255;
        void* p = base + off;
        off += bytes;
        return p;
    };

    // --- zero-init 16-bit region ---
    size_t us_begin = (off + 255) & ~(size_t)255;
    f16* W4h = (f16*)alloc((size_t)3200 * KP4 * 2);
    f16* W5h = (f16*)alloc((size_t)2048 * KP5 * 2);
    unsigned short* L1h = (unsigned short*)alloc((size_t)896 * KPL1 * 2);
    unsigned short* L1l = (unsigned short*)alloc((size_t)896 * KPL1 * 2);
    unsigned short* Fh  = (unsigned short*)alloc((size_t)BATCH * KPL1 * 2);
    unsigned short* Fl  = (unsigned short*)alloc((size_t)BATCH * KPL1 * 2);
    unsigned short* Fc1h  = (unsigned short*)alloc((size_t)256 * 64 * 2);
    unsigned short* Fc1l  = (unsigned short*)alloc((size_t)256 * 64 * 2);
    unsigned short* Fc21h = (unsigned short*)alloc((size_t)128 * 64 * 2);
    unsigned short* Fc21l = (unsigned short*)alloc((size_t)128 * 64 * 2);
    const int CH = 20;
    unsigned short* H1h = (unsigned short*)alloc((size_t)CH * BATCH * 64 * 2);
    unsigned short* H1l = (unsigned short*)alloc((size_t)CH * BATCH * 64 * 2);
    f16* A4[2]; f16* A5[2];
    for (int p = 0; p < 2; ++p) {
        A4[p] = (f16*)alloc((size_t)BATCH * KP4 * 2);
        A5[p] = (f16*)alloc((size_t)BATCH * KP5 * 2);
    }
    size_t us_end = off;

    // --- zero-init fp32 region ---
    size_t fz_begin = (off + 255) & ~(size_t)255;
    float* c2   = (float*)alloc((size_t)BATCH * MID_O * 4);
    float* c3   = (float*)alloc((size_t)BATCH * OUT_DIM * 4);
    float* hb1  = (float*)alloc((size_t)BATCH * MID_I * 4);
    float* cb1  = (float*)alloc((size_t)BATCH * MID_I * 4);
    float* hb21 = (float*)alloc((size_t)BATCH * LATENT * 4);
    float* cb21 = (float*)alloc((size_t)BATCH * LATENT * 4);
    size_t fz_end = off;

    // --- no-init buffers ---
    float* bp4   = (float*)alloc((size_t)4 * MID_O * 4);
    float* bp5   = (float*)alloc((size_t)4 * OUT_DIM * 4);
    float* bs1   = (float*)alloc((size_t)4 * MID_I * 4);
    float* bs21  = (float*)alloc((size_t)4 * LATENT * 4);
    f16*   w2p   = (f16*)alloc((size_t)LATENT * OUT_DIM * 2);
    f16*   W3p   = (f16*)alloc((size_t)70 * 200 * 2);
    float* mu1   = (float*)alloc((size_t)BATCH * V_MID * 4);
    float* mu    = (float*)alloc((size_t)BATCH * V_LAT * 4);
    float* h_t   = (float*)alloc((size_t)BATCH * V_LAT * 4);
    float* c_t   = (float*)alloc((size_t)BATCH * V_LAT * 4);
    float* outb  = (float*)alloc((size_t)BATCH * LATENT * 4);
    unsigned short* Xh = (unsigned short*)alloc((size_t)SEQ * BATCH * 64 * 2);
    unsigned short* Xl = (unsigned short*)alloc((size_t)SEQ * BATCH * 64 * 2);
    float* xp1c  = (float*)alloc((size_t)CH * BATCH * 4 * MID_I * 4);
    float* xp21c = (float*)alloc((size_t)CH * BATCH * 4 * LATENT * 4);

    hipMemsetAsync(base + us_begin, 0, us_end - us_begin, stream);
    hipMemsetAsync(base + fz_begin, 0, fz_end - fz_begin, stream);

    // --- weight/bias packing ---
    pack_f16<<<(3200 * 50  + 255) / 256, 256, 0, stream>>>(l4_wih, 3200 * 50,  50,  KP4, 0,   800, W4h);
    pack_f16<<<(3200 * 800 + 255) / 256, 256, 0, stream>>>(l4_whh, 3200 * 800, 800, KP4, 64,  800, W4h);
    pack_f16<<<(2048 * 800 + 255) / 256, 256, 0, stream>>>(l5_wih, 2048 * 800, 800, KP5, 0,   512, W5h);
    pack_f16<<<(2048 * 512 + 255) / 256, 256, 0, stream>>>(l5_whh, 2048 * 512, 512, KP5, 832, 512, W5h);
    split_pack_lin1<<<(V_MID * LATENT * SEQ + 255) / 256, 256, 0, stream>>>(lin1_w, L1h, L1l);
    split_pack_rows<<<(240 * 64 + 255) / 256, 256, 0, stream>>>(fc1_wih, 240 * 64, 64, 64, Fc1h, Fc1l);
    split_pack_rows<<<(80 * 60 + 255) / 256, 256, 0, stream>>>(fc21_wih, 80 * 60, 60, 64, Fc21h, Fc21l);
    split_pack_rows<<<(SEQ * BATCH * 64 + 255) / 256, 256, 0, stream>>>(x, SEQ * BATCH * 64, 64, 64, Xh, Xl);
    pack_flat_f16<<<(LATENT * OUT_DIM + 255) / 256, 256, 0, stream>>>(down2_w, LATENT * OUT_DIM, w2p);
    pack_l3<<<(70 * 200 + 255) / 256, 256, 0, stream>>>(l3_wih, l3_whh, W3p);
    bias_pack<<<(4 * MID_O   + 255) / 256, 256, 0, stream>>>(l4_bih, l4_bhh, MID_O,   bp4);
    bias_pack<<<(4 * OUT_DIM + 255) / 256, 256, 0, stream>>>(l5_bih, l5_bhh, OUT_DIM, bp5);
    bias_sum<<<1, 256, 0, stream>>>(fc1_bih, fc1_bhh, 4 * MID_I, bs1);
    bias_sum<<<1, 256, 0, stream>>>(fc21_bih, fc21_bhh, 4 * LATENT, bs21);

    // ---------------- encoder ----------------
    for (int c0 = 0; c0 < SEQ; c0 += CH) {
        {
            dim3 g(2, CH * BATCH / 128);
            gemm_mfma0<false><<<g, 256, 0, stream>>>(
                Xh + (size_t)c0 * BATCH * 64, Xl + (size_t)c0 * BATCH * 64,
                Fc1h, Fc1l, 64, 4 * MID_I, bs1, xp1c);
        }
        enc_rec1<<<BATCH / 4, 256, 0, stream>>>(xp1c, CH, fc1_whh, hb1, cb1, H1h, H1l);
        {
            dim3 g(1, CH * BATCH / 128);
            gemm_mfma0<false><<<g, 256, 0, stream>>>(
                H1h, H1l, Fc21h, Fc21l, 64, 4 * LATENT, bs21, xp21c);
        }
        enc_rec21<<<BATCH / 4, 256, 0, stream>>>(xp21c, CH, c0, fc21_whh, hb21, cb21, Fh, Fl);
    }

    // lin1 (bf16 3-term MFMA) + lin2 (fp32)
    {
        dim3 g(7, 16);
        gemm_mfma0<true><<<g, 256, 0, stream>>>(Fh, Fl, L1h, L1l, KPL1, V_MID, lin1_b, mu1);
    }
    {
        dim3 g((V_LAT + BN - 1) / BN, BATCH / BM);
        gemm2k<false, true><<<g, 256, 0, stream>>>(mu1, V_MID, nullptr, 0,
            lin2_w, nullptr, lin2_b, nullptr, mu, BATCH, V_LAT);
    }

    // ---------------- decoder init ----------------
    hipMemcpyAsync(h_t, mu, (size_t)BATCH * V_LAT * 4, hipMemcpyDeviceToDevice, stream);
    {
        dim3 g(1, BATCH / BM);
        gemm2k<false, false><<<g, 256, 0, stream>>>(mu, V_LAT, nullptr, 0,
            idlin_w, nullptr, idlin_b, nullptr, c_t, BATCH, V_LAT);
        gemm2k<false, false><<<g, 256, 0, stream>>>(mu, V_LAT, nullptr, 0,
            down1_w, nullptr, down1_b, nullptr, outb, BATCH, LATENT);
    }

    // ---------------- decoder scan ----------------
    for (int t = 0; t < SEQ; ++t) {
        const int p = t & 1;
        if (t == 0) {
            dec_l3<<<BATCH / 4, 256, 0, stream>>>(outb, l3_wih, l3_whh, l3_bih, l3_bhh,
                                                  h_t, c_t, A4[0]);
        } else {
            dec_step3<<<BATCH / 8, 512, 0, stream>>>(
                out + (size_t)(t - 1) * BATCH * OUT_DIM,
                w2p, down2_b, W3p, l3_bih, l3_bhh,
                h_t, c_t, A4[p]);
        }
        {
            // l4: 25 col x 16 row tiles = 400 blocks; each XCD owns 2 row-tiles
            gemm_dec<1><<<dim3(400), 256, 0, stream>>>(
                A4[p], W4h, KP4, KP4 / 32, MID_O, 2, bp4, c2,
                A4[p ^ 1], KP4, 64,
                A5[p], KP5, 0,
                nullptr);
        }
        {
            // l5: 16 col x 16 row tiles = 256 blocks; each XCD owns 2 row-tiles
            gemm_dec<2><<<dim3(256), 256, 0, stream>>>(
                A5[p], W5h, KP5, KP5 / 32, OUT_DIM, 2, bp5, c3,
                A5[p ^ 1], KP5, 832,
                nullptr, 0, 0,
                out + (size_t)t * BATCH * OUT_DIM);
        }
    }

    hipMemcpyAsync(out + (size_t)SEQ * BATCH * OUT_DIM, mu,
                   (size_t)BATCH * V_LAT * 4, hipMemcpyDeviceToDevice, stream);
}